// Round 1
// baseline (20.542 us; speedup 1.0000x reference)
//
#include <hip/hip_runtime.h>
#include <math.h>

#define BB 1024
#define DD 128
#define TILE 64
#define KC 64
#define LDP (KC + 1)

constexpr float EPSF = 1e-6f;
constexpr float MARGINF = 1.0f;

// ws layout (floats): [0..BB) d_ap, [BB..2BB) ta, [2BB..3BB) tb, [3BB..3BB+256) partials

__global__ __launch_bounds__(256) void row_stats_k(const float* __restrict__ a,
                                                   const float* __restrict__ b,
                                                   float* __restrict__ ws) {
    const int row  = blockIdx.x * 4 + (threadIdx.x >> 6);
    const int lane = threadIdx.x & 63;
    const float* ar = a + (size_t)row * DD;
    const float* br = b + (size_t)row * DD;
    float s_ap = 0.f, s_a2 = 0.f, s_a = 0.f, s_b2 = 0.f, s_b = 0.f;
#pragma unroll
    for (int i = 0; i < 2; ++i) {
        const int d = lane + i * 64;
        const float av = ar[d], bv = br[d];
        const float diff = av - bv + EPSF;
        s_ap = fmaf(diff, diff, s_ap);
        s_a2 = fmaf(av, av, s_a2);
        s_a += av;
        s_b2 = fmaf(bv, bv, s_b2);
        s_b += bv;
    }
#pragma unroll
    for (int off = 32; off >= 1; off >>= 1) {
        s_ap += __shfl_down(s_ap, off);
        s_a2 += __shfl_down(s_a2, off);
        s_a  += __shfl_down(s_a,  off);
        s_b2 += __shfl_down(s_b2, off);
        s_b  += __shfl_down(s_b,  off);
    }
    if (lane == 0) {
        ws[row]          = sqrtf(s_ap);
        ws[BB + row]     = fmaf(2.f * EPSF, s_a, s_a2);
        ws[2 * BB + row] = fmaf(-2.f * EPSF, s_b, s_b2);
    }
}

__global__ __launch_bounds__(256) void triplet_main_k(const float* __restrict__ a,
                                                      const float* __restrict__ b,
                                                      const float* __restrict__ ws,
                                                      float* __restrict__ partials) {
    __shared__ float As[TILE * LDP];
    __shared__ float Bs[TILE * LDP];
    const int j0  = blockIdx.y * TILE;
    const int k0  = blockIdx.x * TILE;
    const int tid = threadIdx.x;

    const int tx = tid & 15;   // col group
    const int ty = tid >> 4;   // row group
    const int jj = ty * 4;
    const int kk = tx * 4;

    float acc[4][4] = {{0.f, 0.f, 0.f, 0.f},
                       {0.f, 0.f, 0.f, 0.f},
                       {0.f, 0.f, 0.f, 0.f},
                       {0.f, 0.f, 0.f, 0.f}};

#pragma unroll
    for (int kh = 0; kh < 2; ++kh) {
        if (kh) __syncthreads();  // protect LDS reuse
        // Stage 64x64 fp32 chunks of A and B; float4 global loads, scalar LDS
        // stores into padded rows ([64][65] -> bank stride 1).
#pragma unroll
        for (int t = 0; t < 4; ++t) {
            const int idx = tid + t * 256;  // 0..1023
            const int r = idx >> 4;         // 0..63
            const int c = idx & 15;         // 0..15 (float4 col)
            const float4 av = reinterpret_cast<const float4*>(
                a + (size_t)(j0 + r) * DD + kh * KC)[c];
            const float4 bv = reinterpret_cast<const float4*>(
                b + (size_t)(k0 + r) * DD + kh * KC)[c];
            float* as = &As[r * LDP + c * 4];
            as[0] = av.x; as[1] = av.y; as[2] = av.z; as[3] = av.w;
            float* bs = &Bs[r * LDP + c * 4];
            bs[0] = bv.x; bs[1] = bv.y; bs[2] = bv.z; bs[3] = bv.w;
        }
        __syncthreads();

#pragma unroll 4
        for (int k = 0; k < KC; ++k) {
            float av[4], bv[4];
#pragma unroll
            for (int i = 0; i < 4; ++i) av[i] = As[(jj + i) * LDP + k];
#pragma unroll
            for (int i = 0; i < 4; ++i) bv[i] = Bs[(kk + i) * LDP + k];
#pragma unroll
            for (int i = 0; i < 4; ++i)
#pragma unroll
                for (int j = 0; j < 4; ++j)
                    acc[i][j] = fmaf(av[i], bv[j], acc[i][j]);
        }
    }

    // Fused epilogue: D = sqrt(ta[j] + tb[k] + D*eps^2 - 2*dot), accumulate
    // relu(d_ap[j] - D + margin) excluding the diagonal.
    const float Ceps = (float)DD * EPSF * EPSF;
    float local = 0.f;
#pragma unroll
    for (int i = 0; i < 4; ++i) {
        const int row  = j0 + jj + i;
        const float ta  = ws[BB + row];
        const float dap = ws[row];
#pragma unroll
        for (int j = 0; j < 4; ++j) {
            const int col = k0 + kk + j;
            const float tb = ws[2 * BB + col];
            float d2 = ta + tb + Ceps - 2.f * acc[i][j];
            d2 = fmaxf(d2, 0.f);
            const float dn = sqrtf(d2);
            if (row != col) local += fmaxf(dap - dn + MARGINF, 0.f);
        }
    }

    // Block reduction: wave shuffle + tiny LDS
#pragma unroll
    for (int off = 32; off >= 1; off >>= 1) local += __shfl_down(local, off);
    __shared__ float red[4];
    if ((tid & 63) == 0) red[tid >> 6] = local;
    __syncthreads();
    if (tid == 0)
        partials[blockIdx.y * gridDim.x + blockIdx.x] = red[0] + red[1] + red[2] + red[3];
}

__global__ __launch_bounds__(256) void finalize_k(const float* __restrict__ partials,
                                                  float* __restrict__ out) {
    const int tid = threadIdx.x;
    float v = partials[tid];  // exactly 256 partials
#pragma unroll
    for (int off = 32; off >= 1; off >>= 1) v += __shfl_down(v, off);
    __shared__ float red[4];
    if ((tid & 63) == 0) red[tid >> 6] = v;
    __syncthreads();
    if (tid == 0) {
        const float total = red[0] + red[1] + red[2] + red[3];
        out[0] = total / (float)((BB - 1) * BB);
    }
}

extern "C" void kernel_launch(void* const* d_in, const int* in_sizes, int n_in,
                              void* d_out, int out_size, void* d_ws, size_t ws_size,
                              hipStream_t stream) {
    const float* a = (const float*)d_in[0];
    const float* b = (const float*)d_in[1];
    float* ws       = (float*)d_ws;
    float* partials = ws + 3 * BB;
    float* out      = (float*)d_out;

    row_stats_k<<<BB / 4, 256, 0, stream>>>(a, b, ws);
    dim3 grid(BB / TILE, BB / TILE);
    triplet_main_k<<<grid, 256, 0, stream>>>(a, b, ws, partials);
    finalize_k<<<1, 256, 0, stream>>>(partials, out);
}